// Round 2
// baseline (663.506 us; speedup 1.0000x reference)
//
#include <hip/hip_runtime.h>
#include <hip/hip_bf16.h>

// KNN top-16: X_test[4096,256] vs X_train[65536,256], fp32 in, int32 idx out.
// Phase 1: fp32->bf16 convert; fp32 train row sq-norms (numpy-pairwise emulation).
// Phase 2: bf16 MFMA approx score GEMM (v = ||b||^2 - 2 a.b), SOFTWARE-
//          PIPELINED: K=64 sub-panels double-buffered in 32 KB LDS, raw
//          s_barrier + COUNTED s_waitcnt vmcnt(4/5) (never 0 in the loop) so
//          global_load_lds prefetch of the next 2 sub-panels stays in flight
//          across barriers AND across the selection phase (T3/T4 pattern).
//          bsq staged through the same vmcnt stream (double-buffered) to keep
//          per-wave vmcnt counts exact. A-fragments preloaded in registers.
//          Selection barriers are lgkmcnt-only; __syncthreads_or replaced by a
//          parity-flagged LDS overflow flag. setprio(1) around MFMA cluster.
// Phase 3: 8 rows/block: approx-top-32 prefilter of 256 candidates (width-32
//          shuffles), then 256 parallel exact fp32-reference-emulating chains,
//          lex (d32, gidx) top-16 (fp32 snap-ties resolve by index like top_k).

typedef short bf16x8 __attribute__((ext_vector_type(8)));
typedef float f32x4 __attribute__((ext_vector_type(4)));
typedef unsigned short ushort_t;
typedef unsigned long long u64;

#define K_DIM     256
#define N_TRAIN   65536
#define N_TEST    4096
#define TM        64
#define TN        128
#define NCHUNK    16
#define CHUNK_N   (N_TRAIN / NCHUNK)      // 4096
#define ITERS     (CHUNK_N / TN)          // 32
#define LISTN     16
#define QCAP      6
#define RPB       8                        // refine rows per block

#define WAITV(N) asm volatile("s_waitcnt vmcnt(" #N ")" ::: "memory")
#define WAITL()  asm volatile("s_waitcnt lgkmcnt(0)" ::: "memory")

// ---------------- numpy pairwise sum emulation (fp32, contract OFF) ----------------
static __device__ __forceinline__ float np_pw_sq128(const float* __restrict__ x) {
    #pragma clang fp contract(off)
    float r0, r1, r2, r3, r4, r5, r6, r7;
    {
        const float4 a = *(const float4*)(x + 0);
        const float4 b = *(const float4*)(x + 4);
        r0 = a.x * a.x; r1 = a.y * a.y; r2 = a.z * a.z; r3 = a.w * a.w;
        r4 = b.x * b.x; r5 = b.y * b.y; r6 = b.z * b.z; r7 = b.w * b.w;
    }
    for (int i = 8; i < 128; i += 8) {
        const float4 a = *(const float4*)(x + i);
        const float4 b = *(const float4*)(x + i + 4);
        r0 = r0 + a.x * a.x; r1 = r1 + a.y * a.y;
        r2 = r2 + a.z * a.z; r3 = r3 + a.w * a.w;
        r4 = r4 + b.x * b.x; r5 = r5 + b.y * b.y;
        r6 = r6 + b.z * b.z; r7 = r7 + b.w * b.w;
    }
    return ((r0 + r1) + (r2 + r3)) + ((r4 + r5) + (r6 + r7));
}

// ---------------- async global->LDS, 16B per lane ----------------
static __device__ __forceinline__ void gld_lds16(const ushort_t* g, ushort_t* l) {
    __builtin_amdgcn_global_load_lds(
        (const __attribute__((address_space(1))) unsigned int*)g,
        (__attribute__((address_space(3))) unsigned int*)l,
        16, 0, 0);
}

// ---------------- Phase 1a: convert ----------------
static __device__ __forceinline__ ushort_t f2bf(float x) {
    unsigned u = __float_as_uint(x);
    return (ushort_t)((u + 0x7FFFu + ((u >> 16) & 1u)) >> 16);  // RNE
}

__global__ __launch_bounds__(256) void convert_bf16(
    const float* __restrict__ src, ushort_t* __restrict__ dst, int nrows)
{
    const int wid = threadIdx.x >> 6, lane = threadIdx.x & 63;
    const int row = blockIdx.x * 4 + wid;
    if (row >= nrows) return;
    const float4 f = *(const float4*)(src + (size_t)row * K_DIM + lane * 4);
    ushort4 h;
    h.x = f2bf(f.x); h.y = f2bf(f.y); h.z = f2bf(f.z); h.w = f2bf(f.w);
    *(ushort4*)(dst + (size_t)row * K_DIM + lane * 4) = h;
}

// ---------------- Phase 1b: train row norms, numpy-pairwise fp32 ----------------
__global__ __launch_bounds__(256) void train_sq_np(
    const float* __restrict__ train, float* __restrict__ bsq)
{
    const int r = blockIdx.x * 256 + threadIdx.x;
    const float* x = train + (size_t)r * K_DIM;
    bsq[r] = np_pw_sq128(x) + np_pw_sq128(x + 128);
}

// ---------------- Phase 2: pipelined approx GEMM + push-based per-row top-16 ----------------
// 256 thr, 2x2 wave grid, wave-tile 32x64. A in registers; B in 2x16KB LDS
// sub-panels (K=64 each), 2-deep prefetch, counted vmcnt.
__global__ __launch_bounds__(256, 4) void knn_approx(
    const ushort_t* __restrict__ testBf, const ushort_t* __restrict__ trainBf,
    const float* __restrict__ bsq, unsigned* __restrict__ cand)
{
    __shared__ __align__(16) ushort_t sB[2][TN * 64];   // 2 x 16 KB, XOR-swizzled
    __shared__ __align__(16) float    sBsq[2][TN];      // 1 KB, double-buffered
    __shared__ __align__(16) unsigned sLv[TM * LISTN];  // 4 KB owner top-16 lists
    __shared__ unsigned sQ  [TM * QCAP];                // 1.5 KB packed-key queues
    __shared__ int      sQn [TM];
    __shared__ unsigned sCutP[TM];
    __shared__ int      sOver[2];                       // parity overflow flags

    const int tid = threadIdx.x;
    const int bx = blockIdx.x;
    const int chunk = bx & (NCHUNK - 1);
    const int rowTile = bx >> 4;                       // 0..63
    const int rowBase = rowTile * TM;
    const int chunkBase = chunk * CHUNK_N;
    const int lane = tid & 63;
    const int wid = tid >> 6;
    const int quad = lane >> 4;
    const int l15 = lane & 15;
    const int wm = wid >> 1;           // 0..1 (row 32-half)
    const int wn = wid & 1;            // 0..1 (col 64-half)

    if (tid < TM) {
        sQn[tid] = 0;
        sCutP[tid] = 0xFFFFFFFFu;
        #pragma unroll
        for (int j = 0; j < LISTN; ++j)
            sLv[tid * LISTN + j] = 0xFFFFF000u | (unsigned)j;   // sentinel keys
    }
    if (tid < 2) sOver[tid] = 0;

    // ---- preload ALL A-fragments into registers (once; 64 VGPR) ----
    bf16x8 af[2][4][2];   // [im][sub-panel][s2]
    {
        const ushort_t* a0 = testBf + (size_t)(rowBase + wm * 32 + l15) * K_DIM + quad * 8;
        const ushort_t* a1 = a0 + (size_t)16 * K_DIM;
        #pragma unroll
        for (int sp = 0; sp < 4; ++sp)
            #pragma unroll
            for (int s2 = 0; s2 < 2; ++s2) {
                af[0][sp][s2] = *(const bf16x8*)(a0 + sp * 64 + s2 * 32);
                af[1][sp][s2] = *(const bf16x8*)(a1 + sp * 64 + s2 * 32);
            }
    }

    // B staging: thread tid -> col c*32 + (tid>>3), k-group slot tid&7 holds
    // kg = (tid&7)^(col&7); LDS byte = c*4096 + (tid>>3)*128 + (tid&7)*16
    //                                = c*4096 + waveBase + lane*16 (linear per wave).
    const int rtS = tid >> 3;                // 0..31
    const int kgS = (tid & 7) ^ (rtS & 7);   // swizzled k-group in memory

    auto stageB = [&](int bufIdx, int t) {
        const int it_ = t >> 2, sp_ = t & 3;
        const ushort_t* gb = trainBf
            + (size_t)(chunkBase + it_ * TN + rtS) * K_DIM + sp_ * 64 + kgS * 8;
        ushort_t* lb = sB[bufIdx] + tid * 8;
        #pragma unroll
        for (int c = 0; c < 4; ++c)
            gld_lds16(gb + (size_t)c * 32 * K_DIM, lb + c * 2048);
        if (sp_ == 0) {
            // all 4 waves issue (vmcnt stays wave-uniform); redundant same-data
            // writes to the same 512B are benign.
            if (lane < 32)
                gld_lds16((const ushort_t*)(bsq + chunkBase + it_ * TN + lane * 4),
                          (ushort_t*)(&sBsq[it_ & 1][0]) + lane * 8);
        }
    };

    // prologue: 2-deep prefetch (5 + 4 loads in flight; A-loads older, also drained
    // by the first counted wait -- conservative, correct).
    stageB(0, 0);
    stageB(1, 1);

    for (int it = 0; it < ITERS; ++it) {
        f32x4 acc[2][4] = {};

        #pragma unroll
        for (int sp = 0; sp < 4; ++sp) {
            // wait own stage(t) loads; leave stage(t+1) in flight.
            // in-flight after wait: sp<3 -> stage(t+1)=4 loads; sp==3 -> next
            // iter's sp0 stage = 5 loads (incl. bsq); last tile -> drain.
            if (sp == 3) {
                if (it == ITERS - 1) { WAITV(0); } else { WAITV(5); }
            } else {
                WAITV(4);
            }
            __builtin_amdgcn_s_barrier();          // all waves' stage(t) landed
            __builtin_amdgcn_sched_barrier(0);

            const ushort_t* sBp = &sB[sp & 1][0];
            __builtin_amdgcn_s_setprio(1);
            #pragma unroll
            for (int s2 = 0; s2 < 2; ++s2)
                #pragma unroll
                for (int in = 0; in < 4; ++in) {
                    const int col = wn * 64 + in * 16 + l15;
                    const int pg = (s2 * 4 + quad) ^ (col & 7);
                    const bf16x8 bfr = *(const bf16x8*)(sBp + col * 64 + pg * 8);
                    acc[0][in] = __builtin_amdgcn_mfma_f32_16x16x32_bf16(af[0][sp][s2], bfr, acc[0][in], 0, 0, 0);
                    acc[1][in] = __builtin_amdgcn_mfma_f32_16x16x32_bf16(af[1][sp][s2], bfr, acc[1][in], 0, 0, 0);
                }
            __builtin_amdgcn_s_setprio(0);

            WAITL();                               // this wave's ds_reads retired
            __builtin_amdgcn_s_barrier();          // all waves done reading buf
            if (sp < 2 || it < ITERS - 1)
                stageB(sp & 1, it * 4 + sp + 2);   // overwrite just-consumed buf
        }

        // v = bsq[col] - 2*dot; C layout: row=quad*4+r, col=l15
        float bq[4];
        unsigned cpk[4];
        #pragma unroll
        for (int in = 0; in < 4; ++in) {
            bq[in] = sBsq[it & 1][wn * 64 + in * 16 + l15];
            cpk[in] = (unsigned)(it * TN + wn * 64 + in * 16 + l15);   // 12-bit col-in-chunk
        }
        #pragma unroll
        for (int im = 0; im < 2; ++im)
            #pragma unroll
            for (int in = 0; in < 4; ++in)
                #pragma unroll
                for (int r = 0; r < 4; ++r)
                    acc[im][in][r] = fmaf(-2.0f, acc[im][in][r], bq[in]);

        // ---- push-based selection; raw barriers (lgkm-only -> prefetch stays
        //      in flight); parity overflow flag replaces __syncthreads_or ----
        unsigned pend = 0xFFFFFFFFu;               // 32 values/thread
        int rnd = 0;
        while (true) {
            unsigned cutr[2][4];
            #pragma unroll
            for (int im = 0; im < 2; ++im)
                #pragma unroll
                for (int r = 0; r < 4; ++r)
                    cutr[im][r] = sCutP[wm * 32 + im * 16 + quad * 4 + r];

            unsigned np = 0u;
            #pragma unroll
            for (int im = 0; im < 2; ++im)
                #pragma unroll
                for (int in = 0; in < 4; ++in)
                    #pragma unroll
                    for (int r = 0; r < 4; ++r) {
                        const int bit = (im * 4 + in) * 4 + r;
                        if ((pend >> bit) & 1u) {
                            const unsigned key =
                                (__float_as_uint(acc[im][in][r] + 1024.0f) & 0xFFFFF000u) | cpk[in];
                            if (key < cutr[im][r]) {
                                const int row = wm * 32 + im * 16 + quad * 4 + r;
                                const int pos = atomicAdd(&sQn[row], 1);
                                if (pos < QCAP) sQ[row * QCAP + pos] = key;
                                else            np |= (1u << bit);
                            }
                        }
                    }
            WAITL();
            __builtin_amdgcn_s_barrier();          // pushes visible
            if (tid < TM) {
                const int nraw = sQn[tid];
                if (nraw > 0) {                    // empty queue (steady state) -> skip
                    unsigned lk[LISTN];
                    #pragma unroll
                    for (int j = 0; j < LISTN; ++j) lk[j] = sLv[tid * LISTN + j];
                    const int n = min(nraw, QCAP);
                    for (int e = 0; e < n; ++e) {
                        const unsigned k = sQ[tid * QCAP + e];
                        if (k < lk[LISTN - 1]) {
                            lk[LISTN - 1] = k;
                            #pragma unroll
                            for (int j = LISTN - 1; j > 0; --j)
                                if (lk[j] < lk[j - 1]) {
                                    const unsigned t = lk[j]; lk[j] = lk[j - 1]; lk[j - 1] = t;
                                }
                        }
                    }
                    #pragma unroll
                    for (int j = 0; j < LISTN; ++j) sLv[tid * LISTN + j] = lk[j];
                    sQn[tid] = 0;
                    sCutP[tid] = lk[LISTN - 1];
                    if (nraw > QCAP) sOver[rnd & 1] = 1;
                }
                if (tid == 0) sOver[(rnd + 1) & 1] = 0;   // reset slot for round rnd+1
            }
            WAITL();
            __builtin_amdgcn_s_barrier();          // drain + cuts + flag visible
            if (sOver[rnd & 1] == 0) break;
            pend = np;
            ++rnd;
        }
    }

    if (tid < TM) {
        #pragma unroll
        for (int j = 0; j < LISTN; ++j)
            cand[(size_t)(rowBase + tid) * (NCHUNK * LISTN) + chunk * LISTN + j] =
                sLv[tid * LISTN + j];
    }
}

// ---------------- Phase 3: prefilter 256->32 + parallel exact fp32 re-rank ----------------
// 8 rows/block, 32 lanes/row; width-32 shuffles.
__global__ __launch_bounds__(256) void knn_refine(
    const float* __restrict__ test, const float* __restrict__ train,
    const float* __restrict__ bsq, const unsigned* __restrict__ cand,
    int* __restrict__ out)
{
    __shared__ __align__(16) float sArow[RPB * K_DIM];   // 8 KB
    __shared__ int sSel[RPB * 32];                       // 1 KB

    const int tid = threadIdx.x;
    const int rowBase = blockIdx.x * RPB;
    const int r = tid >> 5;          // row 0..7
    const int sub = tid & 31;        // lane within row

    {
        const float4* src = (const float4*)(test + (size_t)rowBase * K_DIM);
        float4* dst = (float4*)sArow;
        dst[tid] = src[tid];
        dst[256 + tid] = src[256 + tid];
    }

    u64 ek[8];
    {
        const unsigned* cp = cand + (size_t)(rowBase + r) * 256 + sub * 8;
        #pragma unroll
        for (int j = 0; j < 8; ++j) {
            const unsigned k = cp[j];
            const int chunkId = (sub * 8 + j) >> 4;
            const unsigned gidx = (unsigned)(chunkId * CHUNK_N) + (k & 0xFFFu);
            ek[j] = ((u64)(k & 0xFFFFF000u) << 8) | gidx;
        }
    }
    __syncthreads();

    for (int sel = 0; sel < 32; ++sel) {
        u64 bk = ek[0];
        #pragma unroll
        for (int j = 1; j < 8; ++j) bk = (ek[j] < bk) ? ek[j] : bk;
        #pragma unroll
        for (int off = 16; off > 0; off >>= 1) {
            const u64 ok = __shfl_xor(bk, off, 32);
            bk = (ok < bk) ? ok : bk;
        }
        if (sub == 0) sSel[r * 32 + sel] = (int)(bk & 0xFFFFULL);
        #pragma unroll
        for (int j = 0; j < 8; ++j)
            if (ek[j] == bk) ek[j] = ~0ULL;
    }
    __syncthreads();

    const int gidx = sSel[r * 32 + sub];
    const float* arow = sArow + r * K_DIM;
    const float ta = np_pw_sq128(arow) + np_pw_sq128(arow + 128);
    const float tb = bsq[gidx];

    const float4* bp = (const float4*)(train + (size_t)gidx * K_DIM);
    const float4* ap = (const float4*)arow;
    float c = 0.0f;
    #pragma unroll 8
    for (int k = 0; k < K_DIM / 4; ++k) {
        const float4 a = ap[k];
        const float4 b = bp[k];
        c = fmaf(a.x, b.x, c); c = fmaf(a.y, b.y, c);
        c = fmaf(a.z, b.z, c); c = fmaf(a.w, b.w, c);
    }
    float d32;
    {
        #pragma clang fp contract(off)
        const float t = ta + tb;
        float s = t - 2.0f * c;
        s = fmaxf(s, 0.0f);
        d32 = sqrtf(s);
    }

    u64 fk = ((u64)__float_as_uint(d32) << 32) | (unsigned)gidx;
    for (int sel = 0; sel < 16; ++sel) {
        u64 bk = fk;
        #pragma unroll
        for (int off = 16; off > 0; off >>= 1) {
            const u64 ok = __shfl_xor(bk, off, 32);
            bk = (ok < bk) ? ok : bk;
        }
        if (sub == 0) out[(size_t)(rowBase + r) * 16 + sel] = (int)(bk & 0xFFFFFFFFULL);
        if (fk == bk) fk = ~0ULL;
    }
}

// ---------------- launch ----------------
extern "C" void kernel_launch(void* const* d_in, const int* in_sizes, int n_in,
                              void* d_out, int out_size, void* d_ws, size_t ws_size,
                              hipStream_t stream)
{
    const float* Xtrain = (const float*)d_in[0];   // [65536, 256]
    const float* Xtest  = (const float*)d_in[1];   // [4096, 256]
    int* out = (int*)d_out;                        // [4096, 16] int32

    const size_t OFF_TRAINBF = 0;                              // 33,554,432 B
    const size_t OFF_TESTBF  = 33554432;                       //  2,097,152 B
    const size_t OFF_BSQ     = 35651584;                       //    262,144 B
    const size_t OFF_CAND    = 35913728;                       //  4,194,304 B
    const size_t NEED        = 40108032;
    if (ws_size < NEED) return;

    char* ws = (char*)d_ws;
    ushort_t* trainBf = (ushort_t*)(ws + OFF_TRAINBF);
    ushort_t* testBf  = (ushort_t*)(ws + OFF_TESTBF);
    float*    bsq     = (float*)(ws + OFF_BSQ);
    unsigned* cand    = (unsigned*)(ws + OFF_CAND);

    convert_bf16<<<dim3(N_TRAIN / 4), dim3(256), 0, stream>>>(Xtrain, trainBf, N_TRAIN);
    convert_bf16<<<dim3(N_TEST / 4), dim3(256), 0, stream>>>(Xtest, testBf, N_TEST);
    train_sq_np<<<dim3(N_TRAIN / 256), dim3(256), 0, stream>>>(Xtrain, bsq);
    knn_approx<<<dim3((N_TEST / TM) * NCHUNK), dim3(256), 0, stream>>>(testBf, trainBf, bsq, cand);
    knn_refine<<<dim3(N_TEST / RPB), dim3(256), 0, stream>>>(Xtest, Xtrain, bsq, cand, out);
}

// Round 3
// 576.332 us; speedup vs baseline: 1.1513x; 1.1513x over previous
//
#include <hip/hip_runtime.h>
#include <hip/hip_bf16.h>

// KNN top-16: X_test[4096,256] vs X_train[65536,256], fp32 in, int32 idx out.
// Phase 1: fp32->bf16 convert; fp32 train row sq-norms (numpy-pairwise emulation).
// Phase 2: bf16 MFMA approx score GEMM (v = ||b||^2 - 2 a.b). Round-0 2-phase
//          structure (proven 420 us; round-2 fine-grained pipelining REGRESSED:
//          +9 barriers/iter, FETCH doubled). This round: TM=128 rows/block --
//          each staged 32KB B-panel amortized over 2x rows, halving total
//          staging demand (2GB->1GB) and doubling MFMA per barrier-pair.
//          A-fragments preloaded to registers (128 VGPR), acc in AGPR,
//          __launch_bounds__(256,2) -> 2 blocks/CU. Selection arrays padded
//          (sLv stride 17, sQ stride 9) to kill measured 32-way bank conflicts.
// Phase 3: 8 rows/block: approx-top-32 prefilter of 256 candidates (width-32
//          shuffles), then 256 parallel exact fp32-reference-emulating chains,
//          lex (d32, gidx) top-16 (fp32 snap-ties resolve by index like top_k).

typedef short bf16x8 __attribute__((ext_vector_type(8)));
typedef float f32x4 __attribute__((ext_vector_type(4)));
typedef unsigned short ushort_t;
typedef unsigned long long u64;

#define K_DIM     256
#define N_TRAIN   65536
#define N_TEST    4096
#define TM        128
#define TN        128
#define NCHUNK    16
#define CHUNK_N   (N_TRAIN / NCHUNK)      // 4096
#define ITERS     (CHUNK_N / TN)          // 32
#define LISTN     16
#define LISTP     17                       // padded stride (odd -> 2-way banks)
#define QCAP      8
#define QCAPP     9                        // padded stride
#define RPB       8                        // refine rows per block

// ---------------- numpy pairwise sum emulation (fp32, contract OFF) ----------------
static __device__ __forceinline__ float np_pw_sq128(const float* __restrict__ x) {
    #pragma clang fp contract(off)
    float r0, r1, r2, r3, r4, r5, r6, r7;
    {
        const float4 a = *(const float4*)(x + 0);
        const float4 b = *(const float4*)(x + 4);
        r0 = a.x * a.x; r1 = a.y * a.y; r2 = a.z * a.z; r3 = a.w * a.w;
        r4 = b.x * b.x; r5 = b.y * b.y; r6 = b.z * b.z; r7 = b.w * b.w;
    }
    for (int i = 8; i < 128; i += 8) {
        const float4 a = *(const float4*)(x + i);
        const float4 b = *(const float4*)(x + i + 4);
        r0 = r0 + a.x * a.x; r1 = r1 + a.y * a.y;
        r2 = r2 + a.z * a.z; r3 = r3 + a.w * a.w;
        r4 = r4 + b.x * b.x; r5 = r5 + b.y * b.y;
        r6 = r6 + b.z * b.z; r7 = r7 + b.w * b.w;
    }
    return ((r0 + r1) + (r2 + r3)) + ((r4 + r5) + (r6 + r7));
}

// ---------------- async global->LDS, 16B per lane ----------------
static __device__ __forceinline__ void gld_lds16(const ushort_t* g, ushort_t* l) {
    __builtin_amdgcn_global_load_lds(
        (const __attribute__((address_space(1))) unsigned int*)g,
        (__attribute__((address_space(3))) unsigned int*)l,
        16, 0, 0);
}

// ---------------- Phase 1a: convert ----------------
static __device__ __forceinline__ ushort_t f2bf(float x) {
    unsigned u = __float_as_uint(x);
    return (ushort_t)((u + 0x7FFFu + ((u >> 16) & 1u)) >> 16);  // RNE
}

__global__ __launch_bounds__(256) void convert_bf16(
    const float* __restrict__ src, ushort_t* __restrict__ dst, int nrows)
{
    const int wid = threadIdx.x >> 6, lane = threadIdx.x & 63;
    const int row = blockIdx.x * 4 + wid;
    if (row >= nrows) return;
    const float4 f = *(const float4*)(src + (size_t)row * K_DIM + lane * 4);
    ushort4 h;
    h.x = f2bf(f.x); h.y = f2bf(f.y); h.z = f2bf(f.z); h.w = f2bf(f.w);
    *(ushort4*)(dst + (size_t)row * K_DIM + lane * 4) = h;
}

// ---------------- Phase 1b: train row norms, numpy-pairwise fp32 ----------------
__global__ __launch_bounds__(256) void train_sq_np(
    const float* __restrict__ train, float* __restrict__ bsq)
{
    const int r = blockIdx.x * 256 + threadIdx.x;
    const float* x = train + (size_t)r * K_DIM;
    bsq[r] = np_pw_sq128(x) + np_pw_sq128(x + 128);
}

// ---------------- Phase 2: approx GEMM + push-based per-row top-16 ----------------
// 256 thr, 2x2 wave grid, wave-tile 64x64. A in registers (preloaded), B in 32 KB LDS.
__global__ __launch_bounds__(256, 2) void knn_approx(
    const ushort_t* __restrict__ testBf, const ushort_t* __restrict__ trainBf,
    const float* __restrict__ bsq, unsigned* __restrict__ cand)
{
    __shared__ __align__(16) ushort_t sB[TN * 128];    // 32 KB: 128 cols x 128 k
    __shared__ __align__(16) unsigned sLv[TM * LISTP]; // 8.5 KB padded top-16 lists
    __shared__ unsigned sQ  [TM * QCAPP];              // 4.5 KB padded queues
    __shared__ int      sQn [TM];
    __shared__ unsigned sCutP[TM];
    __shared__ float    sBsq[TN];

    const int tid = threadIdx.x;
    const int bx = blockIdx.x;
    const int chunk = bx & (NCHUNK - 1);               // bx%8 = chunk%8 -> chunk-per-XCD
    const int rowTile = bx >> 4;                       // 0..31
    const int rowBase = rowTile * TM;
    const int chunkBase = chunk * CHUNK_N;
    const int lane = tid & 63;
    const int wid = tid >> 6;
    const int quad = lane >> 4;
    const int l15 = lane & 15;
    const int wm = wid >> 1;           // 0..1 (row 64-half)
    const int wn = wid & 1;            // 0..1 (col 64-half)

    if (tid < TM) {
        sQn[tid] = 0;
        sCutP[tid] = 0xFFFFFFFFu;
        #pragma unroll
        for (int j = 0; j < LISTN; ++j)
            sLv[tid * LISTP + j] = 0xFFFFF000u | (unsigned)j;   // sentinel keys
    }

    // ---- preload ALL A-fragments into registers (once; 128 VGPR) ----
    bf16x8 af[4][2][4];   // [im][panel][s2]
    {
        const ushort_t* a0 = testBf + (size_t)(rowBase + wm * 64 + l15) * K_DIM + quad * 8;
        #pragma unroll
        for (int im = 0; im < 4; ++im)
            #pragma unroll
            for (int p = 0; p < 2; ++p)
                #pragma unroll
                for (int s2 = 0; s2 < 4; ++s2)
                    af[im][p][s2] = *(const bf16x8*)(a0 + (size_t)im * 16 * K_DIM + p * 128 + s2 * 32);
    }

    // B staging constants: slot s = c*256+tid -> col = c*16 + (tid>>4), group u = tid&15
    const int rt = tid >> 4;
    const int ub = tid & 15;
    const int kg = ((ub & 7) ^ (rt & 7)) | (ub & 8);   // c-independent

    for (int it = 0; it < ITERS; ++it) {
        const int colBase = chunkBase + it * TN;
        f32x4 acc[4][4] = {};

        #pragma unroll
        for (int p = 0; p < 2; ++p) {
            if (p) __syncthreads();    // protect sB against prior panel's reads
            {
                const ushort_t* gb = trainBf + (size_t)(colBase + rt) * K_DIM + p * 128 + kg * 8;
                ushort_t* lb = sB + (size_t)tid * 8;
                #pragma unroll
                for (int c = 0; c < 8; ++c)
                    gld_lds16(gb + (size_t)c * 16 * K_DIM, lb + (size_t)c * 2048);
            }
            if (p == 0 && tid < TN) sBsq[tid] = bsq[colBase + tid];
            __syncthreads();           // drains vmcnt -> LDS valid

            #pragma unroll
            for (int s2 = 0; s2 < 4; ++s2) {
                #pragma unroll
                for (int in = 0; in < 4; ++in) {
                    const int col = wn * 64 + in * 16 + l15;
                    const int g = s2 * 4 + quad;
                    const int pg = ((g & 7) ^ (col & 7)) | (g & 8);
                    const bf16x8 bfr = *(const bf16x8*)(sB + (size_t)col * 128 + pg * 8);
                    #pragma unroll
                    for (int im = 0; im < 4; ++im)
                        acc[im][in] = __builtin_amdgcn_mfma_f32_16x16x32_bf16(af[im][p][s2], bfr, acc[im][in], 0, 0, 0);
                }
            }
        }

        // v = bsq[col] - 2*dot; C layout: row=quad*4+r, col=l15
        float bq[4];
        unsigned cpk[4];
        #pragma unroll
        for (int in = 0; in < 4; ++in) {
            bq[in] = sBsq[wn * 64 + in * 16 + l15];
            cpk[in] = (unsigned)(it * TN + wn * 64 + in * 16 + l15);   // 12-bit col-in-chunk
        }
        #pragma unroll
        for (int im = 0; im < 4; ++im)
            #pragma unroll
            for (int in = 0; in < 4; ++in)
                #pragma unroll
                for (int r = 0; r < 4; ++r)
                    acc[im][in][r] = fmaf(-2.0f, acc[im][in][r], bq[in]);

        // ---- push-based selection on packed keys; bounded retry rounds ----
        u64 pend = ~0ULL;                          // 64 values/thread
        while (true) {
            unsigned cutr[4][4];
            #pragma unroll
            for (int im = 0; im < 4; ++im)
                #pragma unroll
                for (int r = 0; r < 4; ++r)
                    cutr[im][r] = sCutP[wm * 64 + im * 16 + quad * 4 + r];

            u64 np = 0ULL;
            #pragma unroll
            for (int im = 0; im < 4; ++im)
                #pragma unroll
                for (int in = 0; in < 4; ++in)
                    #pragma unroll
                    for (int r = 0; r < 4; ++r) {
                        const int bit = (im * 4 + in) * 4 + r;
                        if ((pend >> bit) & 1ULL) {
                            const unsigned key =
                                (__float_as_uint(acc[im][in][r] + 1024.0f) & 0xFFFFF000u) | cpk[in];
                            if (key < cutr[im][r]) {
                                const int row = wm * 64 + im * 16 + quad * 4 + r;
                                const int pos = atomicAdd(&sQn[row], 1);
                                if (pos < QCAP) sQ[row * QCAPP + pos] = key;
                                else            np |= (1ULL << bit);
                            }
                        }
                    }
            __syncthreads();                       // pushes done before drain
            if (tid < TM) {
                const int n = min(sQn[tid], QCAP);
                if (n > 0) {                       // empty queue (steady state) -> skip
                    unsigned lk[LISTN];            // transient regs: 4x ds_read_b128
                    #pragma unroll
                    for (int j = 0; j < LISTN; ++j) lk[j] = sLv[tid * LISTP + j];
                    for (int e = 0; e < n; ++e) {
                        const unsigned k = sQ[tid * QCAPP + e];
                        if (k < lk[LISTN - 1]) {
                            lk[LISTN - 1] = k;
                            #pragma unroll
                            for (int j = LISTN - 1; j > 0; --j)
                                if (lk[j] < lk[j - 1]) {
                                    const unsigned t = lk[j]; lk[j] = lk[j - 1]; lk[j - 1] = t;
                                }
                        }
                    }
                    #pragma unroll
                    for (int j = 0; j < LISTN; ++j) sLv[tid * LISTP + j] = lk[j];
                    sQn[tid] = 0;
                    sCutP[tid] = lk[LISTN - 1];
                }
            }
            if (!__syncthreads_or(np != 0ULL)) break;   // also publishes sCutP/sQn
            pend = np;
        }
    }

    if (tid < TM) {
        #pragma unroll
        for (int j = 0; j < LISTN; ++j)
            cand[(size_t)(rowBase + tid) * (NCHUNK * LISTN) + chunk * LISTN + j] =
                sLv[tid * LISTP + j];
    }
}

// ---------------- Phase 3: prefilter 256->32 + parallel exact fp32 re-rank ----------------
// 8 rows/block, 32 lanes/row; width-32 shuffles.
__global__ __launch_bounds__(256) void knn_refine(
    const float* __restrict__ test, const float* __restrict__ train,
    const float* __restrict__ bsq, const unsigned* __restrict__ cand,
    int* __restrict__ out)
{
    __shared__ __align__(16) float sArow[RPB * K_DIM];   // 8 KB
    __shared__ int sSel[RPB * 32];                       // 1 KB

    const int tid = threadIdx.x;
    const int rowBase = blockIdx.x * RPB;
    const int r = tid >> 5;          // row 0..7
    const int sub = tid & 31;        // lane within row

    {
        const float4* src = (const float4*)(test + (size_t)rowBase * K_DIM);
        float4* dst = (float4*)sArow;
        dst[tid] = src[tid];
        dst[256 + tid] = src[256 + tid];
    }

    u64 ek[8];
    {
        const unsigned* cp = cand + (size_t)(rowBase + r) * 256 + sub * 8;
        #pragma unroll
        for (int j = 0; j < 8; ++j) {
            const unsigned k = cp[j];
            const int chunkId = (sub * 8 + j) >> 4;
            const unsigned gidx = (unsigned)(chunkId * CHUNK_N) + (k & 0xFFFu);
            ek[j] = ((u64)(k & 0xFFFFF000u) << 8) | gidx;
        }
    }
    __syncthreads();

    for (int sel = 0; sel < 32; ++sel) {
        u64 bk = ek[0];
        #pragma unroll
        for (int j = 1; j < 8; ++j) bk = (ek[j] < bk) ? ek[j] : bk;
        #pragma unroll
        for (int off = 16; off > 0; off >>= 1) {
            const u64 ok = __shfl_xor(bk, off, 32);
            bk = (ok < bk) ? ok : bk;
        }
        if (sub == 0) sSel[r * 32 + sel] = (int)(bk & 0xFFFFULL);
        #pragma unroll
        for (int j = 0; j < 8; ++j)
            if (ek[j] == bk) ek[j] = ~0ULL;
    }
    __syncthreads();

    const int gidx = sSel[r * 32 + sub];
    const float* arow = sArow + r * K_DIM;
    const float ta = np_pw_sq128(arow) + np_pw_sq128(arow + 128);
    const float tb = bsq[gidx];

    const float4* bp = (const float4*)(train + (size_t)gidx * K_DIM);
    const float4* ap = (const float4*)arow;
    float c = 0.0f;
    #pragma unroll 8
    for (int k = 0; k < K_DIM / 4; ++k) {
        const float4 a = ap[k];
        const float4 b = bp[k];
        c = fmaf(a.x, b.x, c); c = fmaf(a.y, b.y, c);
        c = fmaf(a.z, b.z, c); c = fmaf(a.w, b.w, c);
    }
    float d32;
    {
        #pragma clang fp contract(off)
        const float t = ta + tb;
        float s = t - 2.0f * c;
        s = fmaxf(s, 0.0f);
        d32 = sqrtf(s);
    }

    u64 fk = ((u64)__float_as_uint(d32) << 32) | (unsigned)gidx;
    for (int sel = 0; sel < 16; ++sel) {
        u64 bk = fk;
        #pragma unroll
        for (int off = 16; off > 0; off >>= 1) {
            const u64 ok = __shfl_xor(bk, off, 32);
            bk = (ok < bk) ? ok : bk;
        }
        if (sub == 0) out[(size_t)(rowBase + r) * 16 + sel] = (int)(bk & 0xFFFFFFFFULL);
        if (fk == bk) fk = ~0ULL;
    }
}

// ---------------- launch ----------------
extern "C" void kernel_launch(void* const* d_in, const int* in_sizes, int n_in,
                              void* d_out, int out_size, void* d_ws, size_t ws_size,
                              hipStream_t stream)
{
    const float* Xtrain = (const float*)d_in[0];   // [65536, 256]
    const float* Xtest  = (const float*)d_in[1];   // [4096, 256]
    int* out = (int*)d_out;                        // [4096, 16] int32

    const size_t OFF_TRAINBF = 0;                              // 33,554,432 B
    const size_t OFF_TESTBF  = 33554432;                       //  2,097,152 B
    const size_t OFF_BSQ     = 35651584;                       //    262,144 B
    const size_t OFF_CAND    = 35913728;                       //  4,194,304 B
    const size_t NEED        = 40108032;
    if (ws_size < NEED) return;

    char* ws = (char*)d_ws;
    ushort_t* trainBf = (ushort_t*)(ws + OFF_TRAINBF);
    ushort_t* testBf  = (ushort_t*)(ws + OFF_TESTBF);
    float*    bsq     = (float*)(ws + OFF_BSQ);
    unsigned* cand    = (unsigned*)(ws + OFF_CAND);

    convert_bf16<<<dim3(N_TRAIN / 4), dim3(256), 0, stream>>>(Xtrain, trainBf, N_TRAIN);
    convert_bf16<<<dim3(N_TEST / 4), dim3(256), 0, stream>>>(Xtest, testBf, N_TEST);
    train_sq_np<<<dim3(N_TRAIN / 256), dim3(256), 0, stream>>>(Xtrain, bsq);
    knn_approx<<<dim3((N_TEST / TM) * NCHUNK), dim3(256), 0, stream>>>(testBf, trainBf, bsq, cand);
    knn_refine<<<dim3(N_TEST / RPB), dim3(256), 0, stream>>>(Xtest, Xtrain, bsq, cand, out);
}

// Round 4
// 520.403 us; speedup vs baseline: 1.2750x; 1.1075x over previous
//
#include <hip/hip_runtime.h>
#include <hip/hip_bf16.h>

// KNN top-16: X_test[4096,256] vs X_train[65536,256], fp32 in, int32 idx out.
// Phase 1: fp32->bf16 convert; fp32 train row sq-norms (numpy-pairwise emulation).
// Phase 2: bf16 MFMA approx score GEMM (v = ||b||^2 - 2 a.b). Block tile stays
//          128x128 (TM=128 amortization: FETCH 210->29 MB, keep) but now split
//          across 8 WAVES (512 thr), wave-tile 32x64: af 128->64 VGPR, acc 32
//          -> ~110 unified regs -> 4 waves/SIMD, 16 waves/CU (round-3 was 8).
//          Rationale: round-3 showed barrier/phase-skew bound at 2 waves/SIMD
//          (32K cy/iter wall vs ~9K cy pipe demand); more resident waves hide
//          per-barrier skew. 2-phase K-loop, global_load_lds(16B), XOR swizzle,
//          push-based top-16 with QCAP=12 (fewer early retry rounds).
// Phase 3: 8 rows/block: approx-top-32 prefilter of 256 candidates (width-32
//          shuffles), then 256 parallel exact fp32-reference-emulating chains,
//          lex (d32, gidx) top-16 (fp32 snap-ties resolve by index like top_k).

typedef short bf16x8 __attribute__((ext_vector_type(8)));
typedef float f32x4 __attribute__((ext_vector_type(4)));
typedef unsigned short ushort_t;
typedef unsigned long long u64;

#define K_DIM     256
#define N_TRAIN   65536
#define N_TEST    4096
#define TM        128
#define TN        128
#define NCHUNK    16
#define CHUNK_N   (N_TRAIN / NCHUNK)      // 4096
#define ITERS     (CHUNK_N / TN)          // 32
#define LISTN     16
#define LISTP     17                       // padded stride
#define QCAP      12
#define QCAPP     13                       // padded stride
#define RPB       8                        // refine rows per block

// ---------------- numpy pairwise sum emulation (fp32, contract OFF) ----------------
static __device__ __forceinline__ float np_pw_sq128(const float* __restrict__ x) {
    #pragma clang fp contract(off)
    float r0, r1, r2, r3, r4, r5, r6, r7;
    {
        const float4 a = *(const float4*)(x + 0);
        const float4 b = *(const float4*)(x + 4);
        r0 = a.x * a.x; r1 = a.y * a.y; r2 = a.z * a.z; r3 = a.w * a.w;
        r4 = b.x * b.x; r5 = b.y * b.y; r6 = b.z * b.z; r7 = b.w * b.w;
    }
    for (int i = 8; i < 128; i += 8) {
        const float4 a = *(const float4*)(x + i);
        const float4 b = *(const float4*)(x + i + 4);
        r0 = r0 + a.x * a.x; r1 = r1 + a.y * a.y;
        r2 = r2 + a.z * a.z; r3 = r3 + a.w * a.w;
        r4 = r4 + b.x * b.x; r5 = r5 + b.y * b.y;
        r6 = r6 + b.z * b.z; r7 = r7 + b.w * b.w;
    }
    return ((r0 + r1) + (r2 + r3)) + ((r4 + r5) + (r6 + r7));
}

// ---------------- async global->LDS, 16B per lane ----------------
static __device__ __forceinline__ void gld_lds16(const ushort_t* g, ushort_t* l) {
    __builtin_amdgcn_global_load_lds(
        (const __attribute__((address_space(1))) unsigned int*)g,
        (__attribute__((address_space(3))) unsigned int*)l,
        16, 0, 0);
}

// ---------------- Phase 1a: convert ----------------
static __device__ __forceinline__ ushort_t f2bf(float x) {
    unsigned u = __float_as_uint(x);
    return (ushort_t)((u + 0x7FFFu + ((u >> 16) & 1u)) >> 16);  // RNE
}

__global__ __launch_bounds__(256) void convert_bf16(
    const float* __restrict__ src, ushort_t* __restrict__ dst, int nrows)
{
    const int wid = threadIdx.x >> 6, lane = threadIdx.x & 63;
    const int row = blockIdx.x * 4 + wid;
    if (row >= nrows) return;
    const float4 f = *(const float4*)(src + (size_t)row * K_DIM + lane * 4);
    ushort4 h;
    h.x = f2bf(f.x); h.y = f2bf(f.y); h.z = f2bf(f.z); h.w = f2bf(f.w);
    *(ushort4*)(dst + (size_t)row * K_DIM + lane * 4) = h;
}

// ---------------- Phase 1b: train row norms, numpy-pairwise fp32 ----------------
__global__ __launch_bounds__(256) void train_sq_np(
    const float* __restrict__ train, float* __restrict__ bsq)
{
    const int r = blockIdx.x * 256 + threadIdx.x;
    const float* x = train + (size_t)r * K_DIM;
    bsq[r] = np_pw_sq128(x) + np_pw_sq128(x + 128);
}

// ---------------- Phase 2: approx GEMM + push-based per-row top-16 ----------------
// 512 thr, 4x2 wave grid, wave-tile 32x64. A in registers (64 VGPR), B in 32 KB LDS.
__global__ __launch_bounds__(512, 4) void knn_approx(
    const ushort_t* __restrict__ testBf, const ushort_t* __restrict__ trainBf,
    const float* __restrict__ bsq, unsigned* __restrict__ cand)
{
    __shared__ __align__(16) ushort_t sB[TN * 128];    // 32 KB: 128 cols x 128 k
    __shared__ __align__(16) unsigned sLv[TM * LISTP]; // 8.5 KB padded top-16 lists
    __shared__ unsigned sQ  [TM * QCAPP];              // 6.5 KB padded queues
    __shared__ int      sQn [TM];
    __shared__ unsigned sCutP[TM];
    __shared__ float    sBsq[TN];

    const int tid = threadIdx.x;
    const int bx = blockIdx.x;
    const int chunk = bx & (NCHUNK - 1);               // bx%8 = chunk%8 -> chunk-per-XCD
    const int rowTile = bx >> 4;                       // 0..31
    const int rowBase = rowTile * TM;
    const int chunkBase = chunk * CHUNK_N;
    const int lane = tid & 63;
    const int wid = tid >> 6;                          // 0..7
    const int quad = lane >> 4;
    const int l15 = lane & 15;
    const int wm = wid >> 1;           // 0..3 (row 32-group)
    const int wn = wid & 1;            // 0..1 (col 64-half)

    if (tid < TM) {
        sQn[tid] = 0;
        sCutP[tid] = 0xFFFFFFFFu;
        #pragma unroll
        for (int j = 0; j < LISTN; ++j)
            sLv[tid * LISTP + j] = 0xFFFFF000u | (unsigned)j;   // sentinel keys
    }

    // ---- preload ALL A-fragments into registers (once; 64 VGPR) ----
    bf16x8 af[2][2][4];   // [im][panel][s2]
    {
        const ushort_t* a0 = testBf + (size_t)(rowBase + wm * 32 + l15) * K_DIM + quad * 8;
        const ushort_t* a1 = a0 + (size_t)16 * K_DIM;
        #pragma unroll
        for (int p = 0; p < 2; ++p)
            #pragma unroll
            for (int s2 = 0; s2 < 4; ++s2) {
                af[0][p][s2] = *(const bf16x8*)(a0 + p * 128 + s2 * 32);
                af[1][p][s2] = *(const bf16x8*)(a1 + p * 128 + s2 * 32);
            }
    }

    // B staging: slot s = c*512+tid -> col = c*32 + (tid>>4), group u = tid&15
    const int rt = tid >> 4;                           // 0..31
    const int ub = tid & 15;
    const int kg = ((ub & 7) ^ (rt & 7)) | (ub & 8);   // c-independent (32%8==0)

    for (int it = 0; it < ITERS; ++it) {
        const int colBase = chunkBase + it * TN;
        f32x4 acc[2][4] = {};

        #pragma unroll
        for (int p = 0; p < 2; ++p) {
            if (p) __syncthreads();    // protect sB against prior panel's reads
            {
                const ushort_t* gb = trainBf + (size_t)(colBase + rt) * K_DIM + p * 128 + kg * 8;
                ushort_t* lb = sB + (size_t)tid * 8;
                #pragma unroll
                for (int c = 0; c < 4; ++c)
                    gld_lds16(gb + (size_t)c * 32 * K_DIM, lb + (size_t)c * 4096);
            }
            if (p == 0 && tid < TN) sBsq[tid] = bsq[colBase + tid];
            __syncthreads();           // drains vmcnt -> LDS valid

            #pragma unroll
            for (int s2 = 0; s2 < 4; ++s2) {
                #pragma unroll
                for (int in = 0; in < 4; ++in) {
                    const int col = wn * 64 + in * 16 + l15;
                    const int g = s2 * 4 + quad;
                    const int pg = ((g & 7) ^ (col & 7)) | (g & 8);
                    const bf16x8 bfr = *(const bf16x8*)(sB + (size_t)col * 128 + pg * 8);
                    acc[0][in] = __builtin_amdgcn_mfma_f32_16x16x32_bf16(af[0][p][s2], bfr, acc[0][in], 0, 0, 0);
                    acc[1][in] = __builtin_amdgcn_mfma_f32_16x16x32_bf16(af[1][p][s2], bfr, acc[1][in], 0, 0, 0);
                }
            }
        }

        // v = bsq[col] - 2*dot; C layout: row=quad*4+r, col=l15
        float bq[4];
        unsigned cpk[4];
        #pragma unroll
        for (int in = 0; in < 4; ++in) {
            bq[in] = sBsq[wn * 64 + in * 16 + l15];
            cpk[in] = (unsigned)(it * TN + wn * 64 + in * 16 + l15);   // 12-bit col-in-chunk
        }
        #pragma unroll
        for (int im = 0; im < 2; ++im)
            #pragma unroll
            for (int in = 0; in < 4; ++in)
                #pragma unroll
                for (int r = 0; r < 4; ++r)
                    acc[im][in][r] = fmaf(-2.0f, acc[im][in][r], bq[in]);

        // ---- push-based selection on packed keys; bounded retry rounds ----
        unsigned pend = 0xFFFFFFFFu;               // 32 values/thread
        while (true) {
            unsigned cutr[2][4];
            #pragma unroll
            for (int im = 0; im < 2; ++im)
                #pragma unroll
                for (int r = 0; r < 4; ++r)
                    cutr[im][r] = sCutP[wm * 32 + im * 16 + quad * 4 + r];

            unsigned np = 0u;
            #pragma unroll
            for (int im = 0; im < 2; ++im)
                #pragma unroll
                for (int in = 0; in < 4; ++in)
                    #pragma unroll
                    for (int r = 0; r < 4; ++r) {
                        const int bit = (im * 4 + in) * 4 + r;
                        if ((pend >> bit) & 1u) {
                            const unsigned key =
                                (__float_as_uint(acc[im][in][r] + 1024.0f) & 0xFFFFF000u) | cpk[in];
                            if (key < cutr[im][r]) {
                                const int row = wm * 32 + im * 16 + quad * 4 + r;
                                const int pos = atomicAdd(&sQn[row], 1);
                                if (pos < QCAP) sQ[row * QCAPP + pos] = key;
                                else            np |= (1u << bit);
                            }
                        }
                    }
            __syncthreads();                       // pushes done before drain
            if (tid < TM) {
                const int n = min(sQn[tid], QCAP);
                if (n > 0) {                       // empty queue (steady state) -> skip
                    unsigned lk[LISTN];            // transient regs: 4x ds_read_b128
                    #pragma unroll
                    for (int j = 0; j < LISTN; ++j) lk[j] = sLv[tid * LISTP + j];
                    for (int e = 0; e < n; ++e) {
                        const unsigned k = sQ[tid * QCAPP + e];
                        if (k < lk[LISTN - 1]) {
                            lk[LISTN - 1] = k;
                            #pragma unroll
                            for (int j = LISTN - 1; j > 0; --j)
                                if (lk[j] < lk[j - 1]) {
                                    const unsigned t = lk[j]; lk[j] = lk[j - 1]; lk[j - 1] = t;
                                }
                        }
                    }
                    #pragma unroll
                    for (int j = 0; j < LISTN; ++j) sLv[tid * LISTP + j] = lk[j];
                    sQn[tid] = 0;
                    sCutP[tid] = lk[LISTN - 1];
                }
            }
            if (!__syncthreads_or(np != 0u)) break;   // also publishes sCutP/sQn
            pend = np;
        }
    }

    if (tid < TM) {
        #pragma unroll
        for (int j = 0; j < LISTN; ++j)
            cand[(size_t)(rowBase + tid) * (NCHUNK * LISTN) + chunk * LISTN + j] =
                sLv[tid * LISTP + j];
    }
}

// ---------------- Phase 3: prefilter 256->32 + parallel exact fp32 re-rank ----------------
// 8 rows/block, 32 lanes/row; width-32 shuffles.
__global__ __launch_bounds__(256) void knn_refine(
    const float* __restrict__ test, const float* __restrict__ train,
    const float* __restrict__ bsq, const unsigned* __restrict__ cand,
    int* __restrict__ out)
{
    __shared__ __align__(16) float sArow[RPB * K_DIM];   // 8 KB
    __shared__ int sSel[RPB * 32];                       // 1 KB

    const int tid = threadIdx.x;
    const int rowBase = blockIdx.x * RPB;
    const int r = tid >> 5;          // row 0..7
    const int sub = tid & 31;        // lane within row

    {
        const float4* src = (const float4*)(test + (size_t)rowBase * K_DIM);
        float4* dst = (float4*)sArow;
        dst[tid] = src[tid];
        dst[256 + tid] = src[256 + tid];
    }

    u64 ek[8];
    {
        const unsigned* cp = cand + (size_t)(rowBase + r) * 256 + sub * 8;
        #pragma unroll
        for (int j = 0; j < 8; ++j) {
            const unsigned k = cp[j];
            const int chunkId = (sub * 8 + j) >> 4;
            const unsigned gidx = (unsigned)(chunkId * CHUNK_N) + (k & 0xFFFu);
            ek[j] = ((u64)(k & 0xFFFFF000u) << 8) | gidx;
        }
    }
    __syncthreads();

    for (int sel = 0; sel < 32; ++sel) {
        u64 bk = ek[0];
        #pragma unroll
        for (int j = 1; j < 8; ++j) bk = (ek[j] < bk) ? ek[j] : bk;
        #pragma unroll
        for (int off = 16; off > 0; off >>= 1) {
            const u64 ok = __shfl_xor(bk, off, 32);
            bk = (ok < bk) ? ok : bk;
        }
        if (sub == 0) sSel[r * 32 + sel] = (int)(bk & 0xFFFFULL);
        #pragma unroll
        for (int j = 0; j < 8; ++j)
            if (ek[j] == bk) ek[j] = ~0ULL;
    }
    __syncthreads();

    const int gidx = sSel[r * 32 + sub];
    const float* arow = sArow + r * K_DIM;
    const float ta = np_pw_sq128(arow) + np_pw_sq128(arow + 128);
    const float tb = bsq[gidx];

    const float4* bp = (const float4*)(train + (size_t)gidx * K_DIM);
    const float4* ap = (const float4*)arow;
    float c = 0.0f;
    #pragma unroll 8
    for (int k = 0; k < K_DIM / 4; ++k) {
        const float4 a = ap[k];
        const float4 b = bp[k];
        c = fmaf(a.x, b.x, c); c = fmaf(a.y, b.y, c);
        c = fmaf(a.z, b.z, c); c = fmaf(a.w, b.w, c);
    }
    float d32;
    {
        #pragma clang fp contract(off)
        const float t = ta + tb;
        float s = t - 2.0f * c;
        s = fmaxf(s, 0.0f);
        d32 = sqrtf(s);
    }

    u64 fk = ((u64)__float_as_uint(d32) << 32) | (unsigned)gidx;
    for (int sel = 0; sel < 16; ++sel) {
        u64 bk = fk;
        #pragma unroll
        for (int off = 16; off > 0; off >>= 1) {
            const u64 ok = __shfl_xor(bk, off, 32);
            bk = (ok < bk) ? ok : bk;
        }
        if (sub == 0) out[(size_t)(rowBase + r) * 16 + sel] = (int)(bk & 0xFFFFFFFFULL);
        if (fk == bk) fk = ~0ULL;
    }
}

// ---------------- launch ----------------
extern "C" void kernel_launch(void* const* d_in, const int* in_sizes, int n_in,
                              void* d_out, int out_size, void* d_ws, size_t ws_size,
                              hipStream_t stream)
{
    const float* Xtrain = (const float*)d_in[0];   // [65536, 256]
    const float* Xtest  = (const float*)d_in[1];   // [4096, 256]
    int* out = (int*)d_out;                        // [4096, 16] int32

    const size_t OFF_TRAINBF = 0;                              // 33,554,432 B
    const size_t OFF_TESTBF  = 33554432;                       //  2,097,152 B
    const size_t OFF_BSQ     = 35651584;                       //    262,144 B
    const size_t OFF_CAND    = 35913728;                       //  4,194,304 B
    const size_t NEED        = 40108032;
    if (ws_size < NEED) return;

    char* ws = (char*)d_ws;
    ushort_t* trainBf = (ushort_t*)(ws + OFF_TRAINBF);
    ushort_t* testBf  = (ushort_t*)(ws + OFF_TESTBF);
    float*    bsq     = (float*)(ws + OFF_BSQ);
    unsigned* cand    = (unsigned*)(ws + OFF_CAND);

    convert_bf16<<<dim3(N_TRAIN / 4), dim3(256), 0, stream>>>(Xtrain, trainBf, N_TRAIN);
    convert_bf16<<<dim3(N_TEST / 4), dim3(256), 0, stream>>>(Xtest, testBf, N_TEST);
    train_sq_np<<<dim3(N_TRAIN / 256), dim3(256), 0, stream>>>(Xtrain, bsq);
    knn_approx<<<dim3((N_TEST / TM) * NCHUNK), dim3(512), 0, stream>>>(testBf, trainBf, bsq, cand);
    knn_refine<<<dim3(N_TEST / RPB), dim3(256), 0, stream>>>(Xtest, Xtrain, bsq, cand, out);
}